// Round 1
// baseline (1635.124 us; speedup 1.0000x reference)
//
#include <hip/hip_runtime.h>

// PolyConv: h = sum_k theta[k] * L_sym^k x,  L_sym = I - D^{-1/2} A D^{-1/2}
// N=100000 nodes, E=1600000 edges, F=64 features, 5 theta terms.

constexpr int kF = 64;

__global__ void k_zero(float* __restrict__ p, int n) {
    int i = blockIdx.x * blockDim.x + threadIdx.x;
    if (i < n) p[i] = 0.0f;
}

__global__ void k_deg(const int* __restrict__ dst, float* __restrict__ deg, int E) {
    int e = blockIdx.x * blockDim.x + threadIdx.x;
    if (e < E) atomicAdd(&deg[dst[e]], 1.0f);
}

__global__ void k_dinv(float* __restrict__ deg, int n) {
    int i = blockIdx.x * blockDim.x + threadIdx.x;
    if (i < n) deg[i] = rsqrtf(fmaxf(deg[i], 1.0f));
}

// h = theta0 * x ; feat = x ; agg = 0   (vectorized float4, n4 = N*F/4)
__global__ void k_init(const float4* __restrict__ x, float4* __restrict__ h,
                       float4* __restrict__ feat, float4* __restrict__ agg,
                       int n4, float th0) {
    int i = blockIdx.x * blockDim.x + threadIdx.x;
    if (i < n4) {
        float4 v = x[i];
        feat[i] = v;
        agg[i]  = make_float4(0.f, 0.f, 0.f, 0.f);
        h[i]    = make_float4(th0 * v.x, th0 * v.y, th0 * v.z, th0 * v.w);
    }
}

// One thread per (edge, feature). 64 consecutive lanes share one edge:
// feat gather is a coalesced 256B row read, atomic adds hit a coalesced
// 256B destination row. src/dst/dinv loads are wave-broadcast.
__global__ void k_scatter(const int* __restrict__ src, const int* __restrict__ dst,
                          const float* __restrict__ feat, const float* __restrict__ dinv,
                          float* __restrict__ agg, int E) {
    int t = blockIdx.x * blockDim.x + threadIdx.x;
    int e = t >> 6;
    int f = t & 63;
    if (e < E) {
        int s = src[e];
        int d = dst[e];
        float v = feat[(s << 6) + f] * dinv[s];
        atomicAdd(&agg[(d << 6) + f], v);
    }
}

// v = feat - dinv[row]*agg ; h += theta*v ; (if not last) feat = v, agg = 0
template <bool LAST>
__global__ void k_update(float4* __restrict__ feat, float4* __restrict__ agg,
                         const float* __restrict__ dinv, float4* __restrict__ h,
                         int n4, float theta) {
    int i = blockIdx.x * blockDim.x + threadIdx.x;
    if (i < n4) {
        float di = dinv[i >> 4];            // F/4 = 16 float4 per row
        float4 fv = feat[i];
        float4 av = agg[i];
        float4 v = make_float4(fv.x - di * av.x, fv.y - di * av.y,
                               fv.z - di * av.z, fv.w - di * av.w);
        float4 hv = h[i];
        hv.x += theta * v.x; hv.y += theta * v.y;
        hv.z += theta * v.z; hv.w += theta * v.w;
        h[i] = hv;
        if (!LAST) {
            feat[i] = v;
            agg[i]  = make_float4(0.f, 0.f, 0.f, 0.f);
        }
    }
}

extern "C" void kernel_launch(void* const* d_in, const int* in_sizes, int n_in,
                              void* d_out, int out_size, void* d_ws, size_t ws_size,
                              hipStream_t stream) {
    const float* x  = (const float*)d_in[0];
    const int*   ei = (const int*)d_in[1];   // edge_index [2, E] row-major
    const int N = in_sizes[0] / kF;
    const int E = in_sizes[1] / 2;
    const int* src = ei;
    const int* dst = ei + E;
    float* h = (float*)d_out;

    // workspace layout: dinv [N] | feat [N*F] | agg [N*F]   (~51.6 MB)
    char* ws = (char*)d_ws;
    float* dinv = (float*)ws;
    size_t off = (((size_t)N * 4) + 511) & ~(size_t)511;
    float* feat = (float*)(ws + off);
    off += (size_t)N * kF * 4;
    float* agg = (float*)(ws + off);

    const float theta[5] = {0.6f, -0.4f, 0.3f, -0.2f, 0.1f};
    const int n4 = N * kF / 4;
    const int B = 256;

    k_zero<<<(N + B - 1) / B, B, 0, stream>>>(dinv, N);
    k_deg<<<(E + B - 1) / B, B, 0, stream>>>(dst, dinv, E);
    k_dinv<<<(N + B - 1) / B, B, 0, stream>>>(dinv, N);
    k_init<<<(n4 + B - 1) / B, B, 0, stream>>>((const float4*)x, (float4*)h,
                                               (float4*)feat, (float4*)agg, n4, theta[0]);
    for (int k = 1; k <= 4; ++k) {
        long long tot = (long long)E * kF;
        int blocks = (int)((tot + B - 1) / B);
        k_scatter<<<blocks, B, 0, stream>>>(src, dst, feat, dinv, agg, E);
        if (k < 4)
            k_update<false><<<(n4 + B - 1) / B, B, 0, stream>>>(
                (float4*)feat, (float4*)agg, dinv, (float4*)h, n4, theta[k]);
        else
            k_update<true><<<(n4 + B - 1) / B, B, 0, stream>>>(
                (float4*)feat, (float4*)agg, dinv, (float4*)h, n4, theta[k]);
    }
}

// Round 2
// 872.401 us; speedup vs baseline: 1.8743x; 1.8743x over previous
//
#include <hip/hip_runtime.h>

// PolyConv: h = sum_k theta[k] * L_sym^k x,  L_sym = I - D^{-1/2} A D^{-1/2}
// N=100000 nodes, E=1600000 edges, F=64 features, 5 theta terms.
//
// Round 2: atomic-free aggregation. Build CSR by dst once per launch, then
// one wave per dst node (lane = feature) gathers+accumulates in a single
// VGPR, with the former k_update fused into the epilogue (agg never
// materialized).

constexpr int kF = 64;

__global__ void k_zero_i(int* __restrict__ p, int n) {
    int i = blockIdx.x * blockDim.x + threadIdx.x;
    if (i < n) p[i] = 0;
}

__global__ void k_hist(const int* __restrict__ dst, int* __restrict__ counts, int E) {
    int e = blockIdx.x * blockDim.x + threadIdx.x;
    if (e < E) atomicAdd(&counts[dst[e]], 1);
}

// Per-block exclusive scan of counts -> rp, block sums -> bsum.
__global__ void k_scan1(const int* __restrict__ counts, int* __restrict__ rp,
                        int* __restrict__ bsum, int n) {
    __shared__ int tmp[256];
    int i = blockIdx.x * 256 + threadIdx.x;
    int v = (i < n) ? counts[i] : 0;
    tmp[threadIdx.x] = v;
    __syncthreads();
    for (int o = 1; o < 256; o <<= 1) {
        int t = (threadIdx.x >= (unsigned)o) ? tmp[threadIdx.x - o] : 0;
        __syncthreads();
        tmp[threadIdx.x] += t;
        __syncthreads();
    }
    if (i < n) rp[i] = tmp[threadIdx.x] - v;      // exclusive within block
    if (threadIdx.x == 255) bsum[blockIdx.x] = tmp[255];
}

// Single-block exclusive scan of block sums (nb <= 1024).
__global__ void k_scan2(int* __restrict__ bsum, int nb) {
    __shared__ int tmp[1024];
    int v = ((int)threadIdx.x < nb) ? bsum[threadIdx.x] : 0;
    tmp[threadIdx.x] = v;
    __syncthreads();
    for (int o = 1; o < 1024; o <<= 1) {
        int t = (threadIdx.x >= (unsigned)o) ? tmp[threadIdx.x - o] : 0;
        __syncthreads();
        tmp[threadIdx.x] += t;
        __syncthreads();
    }
    if ((int)threadIdx.x < nb) bsum[threadIdx.x] = tmp[threadIdx.x] - v;
}

// rp[i] += bsum[block]; dinv[i] = rsqrt(max(deg,1)); rp[n] = E.
__global__ void k_scan3(int* __restrict__ rp, const int* __restrict__ bsum,
                        const int* __restrict__ counts, float* __restrict__ dinv,
                        int n, int E) {
    int i = blockIdx.x * 256 + threadIdx.x;
    if (i < n) {
        rp[i] += bsum[blockIdx.x];
        dinv[i] = rsqrtf(fmaxf((float)counts[i], 1.0f));
    }
    if (i == 0) rp[n] = E;
}

// csr[rp[d] + slot] = src[e]; slot handed out by decrementing counts (destroyed).
__global__ void k_fill(const int* __restrict__ src, const int* __restrict__ dst,
                       const int* __restrict__ rp, int* __restrict__ counts,
                       int* __restrict__ csr, int E) {
    int e = blockIdx.x * blockDim.x + threadIdx.x;
    if (e < E) {
        int d = dst[e];
        int pos = atomicSub(&counts[d], 1) - 1;
        csr[rp[d] + pos] = src[e];
    }
}

// h = theta0 * x ; feat = x
__global__ void k_init(const float4* __restrict__ x, float4* __restrict__ h,
                       float4* __restrict__ feat, int n4, float th0) {
    int i = blockIdx.x * blockDim.x + threadIdx.x;
    if (i < n4) {
        float4 v = x[i];
        feat[i] = v;
        h[i] = make_float4(th0 * v.x, th0 * v.y, th0 * v.z, th0 * v.w);
    }
}

// One wave per dst node, lane = feature.
// acc = sum_{s in N(d)} feat[s][lane]*dinv[s]   (coalesced 256B row gathers)
// v = feat[d] - dinv[d]*acc ; h[d] += theta*v ; featout[d] = v (if !LAST)
template <bool LAST>
__global__ void k_gather(const int* __restrict__ rp, const int* __restrict__ csr,
                         const float* __restrict__ featin, const float* __restrict__ dinv,
                         float* __restrict__ featout, float* __restrict__ h,
                         int n, float theta) {
    int wave = (blockIdx.x * blockDim.x + threadIdx.x) >> 6;
    int lane = threadIdx.x & 63;
    if (wave >= n) return;
    int beg = rp[wave];
    int end = rp[wave + 1];
    float acc = 0.0f;
    for (int j = beg; j < end; ++j) {
        int s = csr[j];
        acc += featin[(s << 6) + lane] * dinv[s];
    }
    int idx = (wave << 6) + lane;
    float v = featin[idx] - dinv[wave] * acc;
    h[idx] += theta * v;
    if (!LAST) featout[idx] = v;
}

extern "C" void kernel_launch(void* const* d_in, const int* in_sizes, int n_in,
                              void* d_out, int out_size, void* d_ws, size_t ws_size,
                              hipStream_t stream) {
    const float* x  = (const float*)d_in[0];
    const int*   ei = (const int*)d_in[1];   // edge_index [2, E] row-major
    const int N = in_sizes[0] / kF;
    const int E = in_sizes[1] / 2;
    const int* src = ei;
    const int* dst = ei + E;
    float* h = (float*)d_out;

    // workspace layout (512B-aligned chunks), ~58.8 MB total:
    // counts[N] | rp[N+1] | bsum[1024] | csr[E] | dinv[N] | featA[N*F] | featB[N*F]
    char* ws = (char*)d_ws;
    size_t off = 0;
    auto carve = [&](size_t bytes) {
        void* p = ws + off;
        off = (off + bytes + 511) & ~(size_t)511;
        return p;
    };
    int*   counts = (int*)carve((size_t)N * 4);
    int*   rp     = (int*)carve((size_t)(N + 1) * 4);
    int*   bsum   = (int*)carve(1024 * 4);
    int*   csr    = (int*)carve((size_t)E * 4);
    float* dinv   = (float*)carve((size_t)N * 4);
    float* featA  = (float*)carve((size_t)N * kF * 4);
    float* featB  = (float*)carve((size_t)N * kF * 4);

    const float theta[5] = {0.6f, -0.4f, 0.3f, -0.2f, 0.1f};
    const int n4 = N * kF / 4;
    const int B = 256;
    const int nb = (N + 255) / 256;          // 391 blocks, <= 1024 for scan2

    // ---- CSR build (by dst) ----
    k_zero_i<<<(N + B - 1) / B, B, 0, stream>>>(counts, N);
    k_hist<<<(E + B - 1) / B, B, 0, stream>>>(dst, counts, E);
    k_scan1<<<nb, 256, 0, stream>>>(counts, rp, bsum, N);
    k_scan2<<<1, 1024, 0, stream>>>(bsum, nb);
    k_scan3<<<nb, 256, 0, stream>>>(rp, bsum, counts, dinv, N, E);
    k_fill<<<(E + B - 1) / B, B, 0, stream>>>(src, dst, rp, counts, csr, E);

    // ---- init ----
    k_init<<<(n4 + B - 1) / B, B, 0, stream>>>((const float4*)x, (float4*)h,
                                               (float4*)featA, n4, theta[0]);

    // ---- 4 fused gather+update passes, ping-pong featA/featB ----
    const int gblocks = (N + 3) / 4;         // 4 waves (nodes) per 256-thread block
    float* fin = featA;
    float* fout = featB;
    for (int k = 1; k <= 4; ++k) {
        if (k < 4) {
            k_gather<false><<<gblocks, 256, 0, stream>>>(rp, csr, fin, dinv, fout, h, N, theta[k]);
            float* t = fin; fin = fout; fout = t;
        } else {
            k_gather<true><<<gblocks, 256, 0, stream>>>(rp, csr, fin, dinv, nullptr, h, N, theta[k]);
        }
    }
}

// Round 3
// 545.022 us; speedup vs baseline: 3.0001x; 1.6007x over previous
//
#include <hip/hip_runtime.h>

// PolyConv: h = sum_k theta[k] * L_sym^k x,  L_sym = I - D^{-1/2} A D^{-1/2}
// N=100000 nodes, E=1600000 edges, F=64 features, 5 theta terms.
//
// Round 3: float4-vectorized gather (4 rows / wave-iteration => 4x MLP),
// k_init fused into the first gather pass.

constexpr int kF = 64;

__global__ void k_zero_i(int* __restrict__ p, int n) {
    int i = blockIdx.x * blockDim.x + threadIdx.x;
    if (i < n) p[i] = 0;
}

__global__ void k_hist(const int* __restrict__ dst, int* __restrict__ counts, int E) {
    int e = blockIdx.x * blockDim.x + threadIdx.x;
    if (e < E) atomicAdd(&counts[dst[e]], 1);
}

// Per-block exclusive scan of counts -> rp, block sums -> bsum.
__global__ void k_scan1(const int* __restrict__ counts, int* __restrict__ rp,
                        int* __restrict__ bsum, int n) {
    __shared__ int tmp[256];
    int i = blockIdx.x * 256 + threadIdx.x;
    int v = (i < n) ? counts[i] : 0;
    tmp[threadIdx.x] = v;
    __syncthreads();
    for (int o = 1; o < 256; o <<= 1) {
        int t = (threadIdx.x >= (unsigned)o) ? tmp[threadIdx.x - o] : 0;
        __syncthreads();
        tmp[threadIdx.x] += t;
        __syncthreads();
    }
    if (i < n) rp[i] = tmp[threadIdx.x] - v;      // exclusive within block
    if (threadIdx.x == 255) bsum[blockIdx.x] = tmp[255];
}

// Single-block exclusive scan of block sums (nb <= 1024).
__global__ void k_scan2(int* __restrict__ bsum, int nb) {
    __shared__ int tmp[1024];
    int v = ((int)threadIdx.x < nb) ? bsum[threadIdx.x] : 0;
    tmp[threadIdx.x] = v;
    __syncthreads();
    for (int o = 1; o < 1024; o <<= 1) {
        int t = (threadIdx.x >= (unsigned)o) ? tmp[threadIdx.x - o] : 0;
        __syncthreads();
        tmp[threadIdx.x] += t;
        __syncthreads();
    }
    if ((int)threadIdx.x < nb) bsum[threadIdx.x] = tmp[threadIdx.x] - v;
}

// rp[i] += bsum[block]; dinv[i] = rsqrt(max(deg,1)); rp[n] = E.
__global__ void k_scan3(int* __restrict__ rp, const int* __restrict__ bsum,
                        const int* __restrict__ counts, float* __restrict__ dinv,
                        int n, int E) {
    int i = blockIdx.x * 256 + threadIdx.x;
    if (i < n) {
        rp[i] += bsum[blockIdx.x];
        dinv[i] = rsqrtf(fmaxf((float)counts[i], 1.0f));
    }
    if (i == 0) rp[n] = E;
}

// csr[rp[d] + slot] = src[e]; slot handed out by decrementing counts (destroyed).
__global__ void k_fill(const int* __restrict__ src, const int* __restrict__ dst,
                       const int* __restrict__ rp, int* __restrict__ counts,
                       int* __restrict__ csr, int E) {
    int e = blockIdx.x * blockDim.x + threadIdx.x;
    if (e < E) {
        int d = dst[e];
        int pos = atomicSub(&counts[d], 1) - 1;
        csr[rp[d] + pos] = src[e];
    }
}

// One wave per dst node. Lane l: group g = l>>4 (one of 4 rows per
// iteration), quad c = l&15 (16B feature slice). Each wave-iteration
// gathers 4 full 256B rows (1KB in flight per load instruction).
// Cross-group reduction: shfl_xor butterflies over lanes 16, 32.
// Epilogue (lanes 0..15): v = feat[d] - dinv[d]*acc;
//   FIRST: h[d] = th0*feat[d] + theta*v   (h never read -> poison-safe)
//   else:  h[d] += theta*v
//   !LAST: featout[d] = v
template <bool FIRST, bool LAST>
__global__ void k_gather(const int* __restrict__ rp, const int* __restrict__ csr,
                         const float* __restrict__ featin, const float* __restrict__ dinv,
                         float* __restrict__ featout, float* __restrict__ h,
                         int n, float th0, float theta) {
    int node = (blockIdx.x * blockDim.x + threadIdx.x) >> 6;
    if (node >= n) return;
    int lane = threadIdx.x & 63;
    int g = lane >> 4;
    int c = lane & 15;
    int beg = rp[node];
    int end = rp[node + 1];

    float4 acc = make_float4(0.f, 0.f, 0.f, 0.f);
    for (int base = beg; base < end; base += 4) {
        int j = base + g;
        int jj = (j < end) ? j : (end - 1);     // loop body implies end > beg
        int s = csr[jj];
        float w = (j < end) ? dinv[s] : 0.0f;
        float4 row = *(const float4*)(featin + ((size_t)s << 6) + (c << 2));
        acc.x += w * row.x;
        acc.y += w * row.y;
        acc.z += w * row.z;
        acc.w += w * row.w;
    }
    // butterfly across the 4 groups (lanes ^16, ^32)
    acc.x += __shfl_xor(acc.x, 16, 64);
    acc.y += __shfl_xor(acc.y, 16, 64);
    acc.z += __shfl_xor(acc.z, 16, 64);
    acc.w += __shfl_xor(acc.w, 16, 64);
    acc.x += __shfl_xor(acc.x, 32, 64);
    acc.y += __shfl_xor(acc.y, 32, 64);
    acc.z += __shfl_xor(acc.z, 32, 64);
    acc.w += __shfl_xor(acc.w, 32, 64);

    if (lane < 16) {
        size_t idx4 = ((size_t)node << 6) + (lane << 2);
        float4 fv = *(const float4*)(featin + idx4);
        float di = dinv[node];
        float4 v = make_float4(fv.x - di * acc.x, fv.y - di * acc.y,
                               fv.z - di * acc.z, fv.w - di * acc.w);
        float4 hv;
        if (FIRST) {
            hv = make_float4(th0 * fv.x + theta * v.x, th0 * fv.y + theta * v.y,
                             th0 * fv.z + theta * v.z, th0 * fv.w + theta * v.w);
        } else {
            hv = *(const float4*)(h + idx4);
            hv.x += theta * v.x; hv.y += theta * v.y;
            hv.z += theta * v.z; hv.w += theta * v.w;
        }
        *(float4*)(h + idx4) = hv;
        if (!LAST) *(float4*)(featout + idx4) = v;
    }
}

extern "C" void kernel_launch(void* const* d_in, const int* in_sizes, int n_in,
                              void* d_out, int out_size, void* d_ws, size_t ws_size,
                              hipStream_t stream) {
    const float* x  = (const float*)d_in[0];
    const int*   ei = (const int*)d_in[1];   // edge_index [2, E] row-major
    const int N = in_sizes[0] / kF;
    const int E = in_sizes[1] / 2;
    const int* src = ei;
    const int* dst = ei + E;
    float* h = (float*)d_out;

    // workspace: counts[N] | rp[N+1] | bsum[1024] | csr[E] | dinv[N] | featA | featB
    char* ws = (char*)d_ws;
    size_t off = 0;
    auto carve = [&](size_t bytes) {
        void* p = ws + off;
        off = (off + bytes + 511) & ~(size_t)511;
        return p;
    };
    int*   counts = (int*)carve((size_t)N * 4);
    int*   rp     = (int*)carve((size_t)(N + 1) * 4);
    int*   bsum   = (int*)carve(1024 * 4);
    int*   csr    = (int*)carve((size_t)E * 4);
    float* dinv   = (float*)carve((size_t)N * 4);
    float* featA  = (float*)carve((size_t)N * kF * 4);
    float* featB  = (float*)carve((size_t)N * kF * 4);

    const float theta[5] = {0.6f, -0.4f, 0.3f, -0.2f, 0.1f};
    const int B = 256;
    const int nb = (N + 255) / 256;          // 391 blocks, <= 1024 for scan2

    // ---- CSR build (by dst) ----
    k_zero_i<<<(N + B - 1) / B, B, 0, stream>>>(counts, N);
    k_hist<<<(E + B - 1) / B, B, 0, stream>>>(dst, counts, E);
    k_scan1<<<nb, 256, 0, stream>>>(counts, rp, bsum, N);
    k_scan2<<<1, 1024, 0, stream>>>(bsum, nb);
    k_scan3<<<nb, 256, 0, stream>>>(rp, bsum, counts, dinv, N, E);
    k_fill<<<(E + B - 1) / B, B, 0, stream>>>(src, dst, rp, counts, csr, E);

    // ---- 4 fused gather+update passes (k=1 also does init), ping-pong ----
    const int gblocks = (N + 3) / 4;         // 4 waves (nodes) per 256-thread block
    k_gather<true, false><<<gblocks, 256, 0, stream>>>(rp, csr, x, dinv, featA, h,
                                                       N, theta[0], theta[1]);
    k_gather<false, false><<<gblocks, 256, 0, stream>>>(rp, csr, featA, dinv, featB, h,
                                                        N, 0.f, theta[2]);
    k_gather<false, false><<<gblocks, 256, 0, stream>>>(rp, csr, featB, dinv, featA, h,
                                                        N, 0.f, theta[3]);
    k_gather<false, true><<<gblocks, 256, 0, stream>>>(rp, csr, featA, dinv, nullptr, h,
                                                       N, 0.f, theta[4]);
}

// Round 4
// 414.102 us; speedup vs baseline: 3.9486x; 1.3162x over previous
//
#include <hip/hip_runtime.h>

// PolyConv: h = sum_k theta[k] * L_sym^k x,  L_sym = I - D^{-1/2} A D^{-1/2}
// N=100000 nodes, E=1600000 edges, F=64 features, 5 theta terms.
//
// Round 4: replace hist+scan+atomic-fill CSR build (k_fill had 16x write
// amplification: 107MB HBM writes for a 6.4MB payload) with a two-phase
// LDS-staged multisplit whose HBM writes are line-dense runs.
//   Phase A: tile-local bucket sort by dst>>9 (K=196 buckets), packed
//            (local_dst<<23)|src, streamed out in coalesced per-bucket runs.
//   Phase B: one block per bucket: LDS per-node counts -> scan -> LDS
//            scatter -> sequential csr write; emits rp + dinv directly.

constexpr int kF = 64;
constexpr int BSHIFT = 9;             // bucket = dst >> 9  (512 nodes/bucket)
constexpr int BW = 1 << BSHIFT;       // 512
constexpr int TILE = 8192;            // edges per phase-A block
constexpr int PB_STAGE = 12288;       // phase-B LDS staging capacity (srcs)
// packing requires src < 2^23 (N=100000 ok) and K <= 256

__global__ void k_zero_i(int* __restrict__ p, int n) {
    int i = blockIdx.x * blockDim.x + threadIdx.x;
    if (i < n) p[i] = 0;
}

// Phase A: multisplit edges into K buckets, LDS-staged for write-combining.
__global__ void k_binA(const int* __restrict__ src, const int* __restrict__ dst,
                       unsigned* __restrict__ pairs, int* __restrict__ gcursor,
                       int E, int K, int cap) {
    __shared__ unsigned sorted[TILE];   // 32 KB
    __shared__ int hist[256];
    __shared__ int stmp[256];
    __shared__ int loff[257];
    __shared__ int lcur[256];
    __shared__ int gb[256];
    const int tid = threadIdx.x;        // blockDim = 256
    const long long tb = (long long)blockIdx.x * TILE;
    const int tcount = (int)min((long long)TILE, (long long)E - tb);

    hist[tid] = 0;
    __syncthreads();
    // pass 1: LDS histogram by bucket
    for (int i = tid; i < tcount; i += 256)
        atomicAdd(&hist[dst[tb + i] >> BSHIFT], 1);
    __syncthreads();
    // exclusive scan of hist (Hillis-Steele, 256 entries)
    int v = hist[tid];
    stmp[tid] = v;
    __syncthreads();
    for (int o = 1; o < 256; o <<= 1) {
        int t = (tid >= o) ? stmp[tid - o] : 0;
        __syncthreads();
        stmp[tid] += t;
        __syncthreads();
    }
    loff[tid] = stmp[tid] - v;
    if (tid == 255) loff[256] = stmp[255];
    lcur[tid] = stmp[tid] - v;
    gb[tid] = (tid < K) ? atomicAdd(&gcursor[tid], v) : 0;  // reserve space
    __syncthreads();
    // pass 2: scatter edges into bucket-sorted LDS order (packed)
    for (int i = tid; i < tcount; i += 256) {
        int d = dst[tb + i];
        int s = src[tb + i];
        int b = d >> BSHIFT;
        int pos = atomicAdd(&lcur[b], 1);
        sorted[pos] = ((unsigned)(d & (BW - 1)) << 23) | (unsigned)s;
    }
    __syncthreads();
    // stream out: coalesced runs per bucket; binary search bucket-of-i
    for (int i = tid; i < tcount; i += 256) {
        int lo = 0, hi = K - 1;
        while (lo < hi) {
            int mid = (lo + hi + 1) >> 1;
            if (loff[mid] <= i) lo = mid; else hi = mid - 1;
        }
        pairs[(size_t)lo * cap + gb[lo] + (i - loff[lo])] = sorted[i];
    }
}

// Exclusive scan of per-bucket edge counts -> gbase (K <= 256, one block).
__global__ void k_scanb(const int* __restrict__ gcursor, int* __restrict__ gbase, int K) {
    __shared__ int stmp[256];
    int tid = threadIdx.x;
    int v = (tid < K) ? gcursor[tid] : 0;
    stmp[tid] = v;
    __syncthreads();
    for (int o = 1; o < 256; o <<= 1) {
        int t = (tid >= o) ? stmp[tid - o] : 0;
        __syncthreads();
        stmp[tid] += t;
        __syncthreads();
    }
    if (tid < K) gbase[tid] = stmp[tid] - v;
}

// Phase B: one block (512 threads) per bucket. Builds csr run sequentially,
// emits rp and dinv for the bucket's node range.
__global__ void k_binB(const unsigned* __restrict__ pairs, const int* __restrict__ gcursor,
                       const int* __restrict__ gbase, int* __restrict__ rp,
                       float* __restrict__ dinv, int* __restrict__ csr,
                       int N, int E, int K, int cap) {
    __shared__ int cnt[BW];
    __shared__ int stmp[BW];
    __shared__ int excl[BW];
    __shared__ int cur[BW];
    __shared__ int staged[PB_STAGE];    // 48 KB
    const int b = blockIdx.x;
    const int tid = threadIdx.x;        // blockDim = 512 (= BW)
    const int ecnt = gcursor[b];
    const int base = gbase[b];
    const unsigned* bp = pairs + (size_t)b * cap;

    cnt[tid] = 0;
    __syncthreads();
    for (int i = tid; i < ecnt; i += BW)
        atomicAdd(&cnt[bp[i] >> 23], 1);
    __syncthreads();
    int v = cnt[tid];
    stmp[tid] = v;
    __syncthreads();
    for (int o = 1; o < BW; o <<= 1) {
        int t = (tid >= o) ? stmp[tid - o] : 0;
        __syncthreads();
        stmp[tid] += t;
        __syncthreads();
    }
    excl[tid] = stmp[tid] - v;
    cur[tid] = stmp[tid] - v;
    __syncthreads();
    for (int i = tid; i < ecnt; i += BW) {
        unsigned p = bp[i];
        int pos = atomicAdd(&cur[p >> 23], 1);
        staged[pos] = (int)(p & 0x7FFFFFu);
    }
    __syncthreads();
    for (int i = tid; i < ecnt; i += BW)
        csr[base + i] = staged[i];                  // sequential, coalesced
    int node = (b << BSHIFT) + tid;
    if (node < N) {
        rp[node] = base + excl[tid];
        dinv[node] = rsqrtf(fmaxf((float)v, 1.0f));
    }
    if (b == K - 1 && tid == 0) rp[N] = E;
}

// One wave per dst node. Lane l: group g = l>>4 (row within 4-row batch),
// quad c = l&15 (16B feature slice). Each wave-iteration gathers 4 rows (1KB).
// Cross-group reduction via shfl_xor(16,32). Epilogue fuses the L_sym update
// and the h accumulation; FIRST pass also does the init (h never read).
template <bool FIRST, bool LAST>
__global__ void k_gather(const int* __restrict__ rp, const int* __restrict__ csr,
                         const float* __restrict__ featin, const float* __restrict__ dinv,
                         float* __restrict__ featout, float* __restrict__ h,
                         int n, float th0, float theta) {
    int node = (blockIdx.x * blockDim.x + threadIdx.x) >> 6;
    if (node >= n) return;
    int lane = threadIdx.x & 63;
    int g = lane >> 4;
    int c = lane & 15;
    int beg = rp[node];
    int end = rp[node + 1];

    float4 acc = make_float4(0.f, 0.f, 0.f, 0.f);
    for (int base = beg; base < end; base += 4) {
        int j = base + g;
        int jj = (j < end) ? j : (end - 1);
        int s = csr[jj];
        float w = (j < end) ? dinv[s] : 0.0f;
        float4 row = *(const float4*)(featin + ((size_t)s << 6) + (c << 2));
        acc.x += w * row.x;
        acc.y += w * row.y;
        acc.z += w * row.z;
        acc.w += w * row.w;
    }
    acc.x += __shfl_xor(acc.x, 16, 64);
    acc.y += __shfl_xor(acc.y, 16, 64);
    acc.z += __shfl_xor(acc.z, 16, 64);
    acc.w += __shfl_xor(acc.w, 16, 64);
    acc.x += __shfl_xor(acc.x, 32, 64);
    acc.y += __shfl_xor(acc.y, 32, 64);
    acc.z += __shfl_xor(acc.z, 32, 64);
    acc.w += __shfl_xor(acc.w, 32, 64);

    if (lane < 16) {
        size_t idx4 = ((size_t)node << 6) + (lane << 2);
        float4 fv = *(const float4*)(featin + idx4);
        float di = dinv[node];
        float4 v = make_float4(fv.x - di * acc.x, fv.y - di * acc.y,
                               fv.z - di * acc.z, fv.w - di * acc.w);
        float4 hv;
        if (FIRST) {
            hv = make_float4(th0 * fv.x + theta * v.x, th0 * fv.y + theta * v.y,
                             th0 * fv.z + theta * v.z, th0 * fv.w + theta * v.w);
        } else {
            hv = *(const float4*)(h + idx4);
            hv.x += theta * v.x; hv.y += theta * v.y;
            hv.z += theta * v.z; hv.w += theta * v.w;
        }
        *(float4*)(h + idx4) = hv;
        if (!LAST) *(float4*)(featout + idx4) = v;
    }
}

extern "C" void kernel_launch(void* const* d_in, const int* in_sizes, int n_in,
                              void* d_out, int out_size, void* d_ws, size_t ws_size,
                              hipStream_t stream) {
    const float* x  = (const float*)d_in[0];
    const int*   ei = (const int*)d_in[1];   // edge_index [2, E] row-major
    const int N = in_sizes[0] / kF;
    const int E = in_sizes[1] / 2;
    const int* src = ei;
    const int* dst = ei + E;
    float* h = (float*)d_out;

    const int K = (N + BW - 1) >> BSHIFT;         // 196 buckets (K <= 256)
    const int cap = 2 * ((E + K - 1) / K);        // per-bucket capacity

    // workspace: gcursor[K] | gbase[K] | rp[N+1] | dinv[N] | csr[E] | featA | featB
    // pairs (K*cap uints, ~12.8MB) aliases featB (dead before featB is written).
    char* ws = (char*)d_ws;
    size_t off = 0;
    auto carve = [&](size_t bytes) {
        void* p = ws + off;
        off = (off + bytes + 511) & ~(size_t)511;
        return p;
    };
    int*      gcursor = (int*)carve((size_t)K * 4);
    int*      gbase   = (int*)carve((size_t)K * 4);
    int*      rp      = (int*)carve((size_t)(N + 1) * 4);
    float*    dinv    = (float*)carve((size_t)N * 4);
    int*      csr     = (int*)carve((size_t)E * 4);
    float*    featA   = (float*)carve((size_t)N * kF * 4);
    float*    featB   = (float*)carve((size_t)N * kF * 4);
    unsigned* pairs   = (unsigned*)featB;          // alias: dead before featB live

    const float theta[5] = {0.6f, -0.4f, 0.3f, -0.2f, 0.1f};

    // ---- CSR build (multisplit) ----
    k_zero_i<<<1, 256, 0, stream>>>(gcursor, K);
    k_binA<<<(E + TILE - 1) / TILE, 256, 0, stream>>>(src, dst, pairs, gcursor, E, K, cap);
    k_scanb<<<1, 256, 0, stream>>>(gcursor, gbase, K);
    k_binB<<<K, BW, 0, stream>>>(pairs, gcursor, gbase, rp, dinv, csr, N, E, K, cap);

    // ---- 4 fused gather+update passes (k=1 also does init), ping-pong ----
    const int gblocks = (N + 3) / 4;               // 4 waves (nodes) per block
    k_gather<true, false><<<gblocks, 256, 0, stream>>>(rp, csr, x, dinv, featA, h,
                                                       N, theta[0], theta[1]);
    k_gather<false, false><<<gblocks, 256, 0, stream>>>(rp, csr, featA, dinv, featB, h,
                                                        N, 0.f, theta[2]);
    k_gather<false, false><<<gblocks, 256, 0, stream>>>(rp, csr, featB, dinv, featA, h,
                                                        N, 0.f, theta[3]);
    k_gather<false, true><<<gblocks, 256, 0, stream>>>(rp, csr, featA, dinv, nullptr, h,
                                                       N, 0.f, theta[4]);
}

// Round 5
// 318.943 us; speedup vs baseline: 5.1267x; 1.2984x over previous
//
#include <hip/hip_runtime.h>

// PolyConv: h = sum_k theta[k] * L_sym^k x,  L_sym = I - D^{-1/2} A D^{-1/2}
// N=100000 nodes, E=1600000 edges, F=64 features, 5 theta terms.
//
// Round 5: bf16 feature table for the gather passes (rows 256B -> 128B,
// halves the L2-miss fill traffic that bounds k_gather; one wave-iteration
// now gathers 8 rows = 1KB). h accumulates in fp32; pass-1 identity term
// reads fp32 x. binA widened to 512 threads.

constexpr int kF = 64;
constexpr int BSHIFT = 9;             // bucket = dst >> 9  (512 nodes/bucket)
constexpr int BW = 1 << BSHIFT;       // 512
constexpr int TILE = 8192;            // edges per phase-A block
constexpr int PB_STAGE = 12288;       // phase-B LDS staging capacity (srcs)

static __device__ __forceinline__ float bfl(unsigned u) {        // low bf16 -> f32
    return __uint_as_float(u << 16);
}
static __device__ __forceinline__ float bfh(unsigned u) {        // high bf16 -> f32
    return __uint_as_float(u & 0xffff0000u);
}
static __device__ __forceinline__ unsigned f2bf(float f) {       // RNE f32 -> bf16
    unsigned u = __float_as_uint(f);
    return (u + 0x7fffu + ((u >> 16) & 1u)) >> 16;
}
static __device__ __forceinline__ unsigned pack2(float a, float b) {
    return f2bf(a) | (f2bf(b) << 16);
}

__global__ void k_zero_i(int* __restrict__ p, int n) {
    int i = blockIdx.x * blockDim.x + threadIdx.x;
    if (i < n) p[i] = 0;
}

// x (fp32) -> xb (bf16), 8 elements per thread.
__global__ void k_cvt(const float4* __restrict__ x4, uint4* __restrict__ xb4, int n8) {
    int i = blockIdx.x * blockDim.x + threadIdx.x;
    if (i < n8) {
        float4 a = x4[2 * i];
        float4 b = x4[2 * i + 1];
        uint4 o;
        o.x = pack2(a.x, a.y);
        o.y = pack2(a.z, a.w);
        o.z = pack2(b.x, b.y);
        o.w = pack2(b.z, b.w);
        xb4[i] = o;
    }
}

// Phase A: multisplit edges into K buckets (LDS-staged, line-dense writes).
__global__ void k_binA(const int* __restrict__ src, const int* __restrict__ dst,
                       unsigned* __restrict__ pairs, int* __restrict__ gcursor,
                       int E, int K, int cap) {
    __shared__ unsigned sorted[TILE];   // 32 KB
    __shared__ int hist[256];
    __shared__ int stmp[256];
    __shared__ int loff[257];
    __shared__ int lcur[256];
    __shared__ int gb[256];
    const int tid = threadIdx.x;        // blockDim = 512
    const long long tb = (long long)blockIdx.x * TILE;
    const int tcount = (int)min((long long)TILE, (long long)E - tb);

    if (tid < 256) hist[tid] = 0;
    __syncthreads();
    for (int i = tid; i < tcount; i += 512)
        atomicAdd(&hist[dst[tb + i] >> BSHIFT], 1);
    __syncthreads();
    int v = (tid < 256) ? hist[tid] : 0;
    if (tid < 256) stmp[tid] = v;
    __syncthreads();
    for (int o = 1; o < 256; o <<= 1) {
        int t = (tid >= o && tid < 256) ? stmp[tid - o] : 0;
        __syncthreads();
        if (tid < 256) stmp[tid] += t;
        __syncthreads();
    }
    if (tid < 256) {
        loff[tid] = stmp[tid] - v;
        lcur[tid] = stmp[tid] - v;
        gb[tid] = (tid < K) ? atomicAdd(&gcursor[tid], v) : 0;
        if (tid == 255) loff[256] = stmp[255];
    }
    __syncthreads();
    for (int i = tid; i < tcount; i += 512) {
        int d = dst[tb + i];
        int s = src[tb + i];
        int b = d >> BSHIFT;
        int pos = atomicAdd(&lcur[b], 1);
        sorted[pos] = ((unsigned)(d & (BW - 1)) << 23) | (unsigned)s;
    }
    __syncthreads();
    for (int i = tid; i < tcount; i += 512) {
        int lo = 0, hi = K - 1;
        while (lo < hi) {
            int mid = (lo + hi + 1) >> 1;
            if (loff[mid] <= i) lo = mid; else hi = mid - 1;
        }
        pairs[(size_t)lo * cap + gb[lo] + (i - loff[lo])] = sorted[i];
    }
}

// Exclusive scan of per-bucket edge counts -> gbase (K <= 256, one block).
__global__ void k_scanb(const int* __restrict__ gcursor, int* __restrict__ gbase, int K) {
    __shared__ int stmp[256];
    int tid = threadIdx.x;
    int v = (tid < K) ? gcursor[tid] : 0;
    stmp[tid] = v;
    __syncthreads();
    for (int o = 1; o < 256; o <<= 1) {
        int t = (tid >= o) ? stmp[tid - o] : 0;
        __syncthreads();
        stmp[tid] += t;
        __syncthreads();
    }
    if (tid < K) gbase[tid] = stmp[tid] - v;
}

// Phase B: one block (512 threads) per bucket -> sequential csr runs, rp, dinv.
__global__ void k_binB(const unsigned* __restrict__ pairs, const int* __restrict__ gcursor,
                       const int* __restrict__ gbase, int* __restrict__ rp,
                       float* __restrict__ dinv, int* __restrict__ csr,
                       int N, int E, int K, int cap) {
    __shared__ int cnt[BW];
    __shared__ int stmp[BW];
    __shared__ int excl[BW];
    __shared__ int cur[BW];
    __shared__ int staged[PB_STAGE];    // 48 KB
    const int b = blockIdx.x;
    const int tid = threadIdx.x;        // blockDim = 512
    const int ecnt = gcursor[b];
    const int base = gbase[b];
    const unsigned* bp = pairs + (size_t)b * cap;

    cnt[tid] = 0;
    __syncthreads();
    for (int i = tid; i < ecnt; i += BW)
        atomicAdd(&cnt[bp[i] >> 23], 1);
    __syncthreads();
    int v = cnt[tid];
    stmp[tid] = v;
    __syncthreads();
    for (int o = 1; o < BW; o <<= 1) {
        int t = (tid >= o) ? stmp[tid - o] : 0;
        __syncthreads();
        stmp[tid] += t;
        __syncthreads();
    }
    excl[tid] = stmp[tid] - v;
    cur[tid] = stmp[tid] - v;
    __syncthreads();
    for (int i = tid; i < ecnt; i += BW) {
        unsigned p = bp[i];
        int pos = atomicAdd(&cur[p >> 23], 1);
        staged[pos] = (int)(p & 0x7FFFFFu);
    }
    __syncthreads();
    for (int i = tid; i < ecnt; i += BW)
        csr[base + i] = staged[i];                  // sequential, coalesced
    int node = (b << BSHIFT) + tid;
    if (node < N) {
        rp[node] = base + excl[tid];
        dinv[node] = rsqrtf(fmaxf((float)v, 1.0f));
    }
    if (b == K - 1 && tid == 0) rp[N] = E;
}

// One wave per dst node, bf16 feature table (128B rows).
// Lane l: group g = l>>3 (one of 8 rows per iteration), c = l&7 (16B = 8
// features). Each wave-iteration gathers 8 rows (1KB). Butterfly over lanes
// ^8,^16,^32 leaves lanes 0..7 with features [lane*8, lane*8+8).
// Epilogue: v = feat[d] - dinv[d]*acc; FIRST uses fp32 x for the identity
// term and writes h fresh (poison-safe); !LAST stores v as bf16.
template <bool FIRST, bool LAST>
__global__ void k_gather(const int* __restrict__ rp, const int* __restrict__ csr,
                         const unsigned short* __restrict__ featin,
                         const float* __restrict__ xf,
                         const float* __restrict__ dinv,
                         unsigned short* __restrict__ featout,
                         float* __restrict__ h,
                         int n, float th0, float theta) {
    int node = (blockIdx.x * blockDim.x + threadIdx.x) >> 6;
    if (node >= n) return;
    int lane = threadIdx.x & 63;
    int g = lane >> 3;
    int c = lane & 7;
    int beg = rp[node];
    int end = rp[node + 1];

    float acc[8] = {0.f, 0.f, 0.f, 0.f, 0.f, 0.f, 0.f, 0.f};
    for (int base = beg; base < end; base += 8) {
        int j = base + g;
        int jj = (j < end) ? j : (end - 1);
        int s = csr[jj];
        float w = (j < end) ? dinv[s] : 0.0f;
        uint4 r = *(const uint4*)(featin + ((size_t)s << 6) + (c << 3));
        acc[0] += w * bfl(r.x);
        acc[1] += w * bfh(r.x);
        acc[2] += w * bfl(r.y);
        acc[3] += w * bfh(r.y);
        acc[4] += w * bfl(r.z);
        acc[5] += w * bfh(r.z);
        acc[6] += w * bfl(r.w);
        acc[7] += w * bfh(r.w);
    }
    #pragma unroll
    for (int m = 8; m < 64; m <<= 1) {
        #pragma unroll
        for (int i = 0; i < 8; ++i)
            acc[i] += __shfl_xor(acc[i], m, 64);
    }

    if (lane < 8) {
        size_t off = ((size_t)node << 6) + (lane << 3);
        float f[8];
        if (FIRST) {
            float4 a = *(const float4*)(xf + off);
            float4 b = *(const float4*)(xf + off + 4);
            f[0] = a.x; f[1] = a.y; f[2] = a.z; f[3] = a.w;
            f[4] = b.x; f[5] = b.y; f[6] = b.z; f[7] = b.w;
        } else {
            uint4 r = *(const uint4*)(featin + off);
            f[0] = bfl(r.x); f[1] = bfh(r.x);
            f[2] = bfl(r.y); f[3] = bfh(r.y);
            f[4] = bfl(r.z); f[5] = bfh(r.z);
            f[6] = bfl(r.w); f[7] = bfh(r.w);
        }
        float di = dinv[node];
        float v[8];
        #pragma unroll
        for (int i = 0; i < 8; ++i) v[i] = f[i] - di * acc[i];
        float4 h0, h1;
        if (FIRST) {
            h0 = make_float4(th0 * f[0] + theta * v[0], th0 * f[1] + theta * v[1],
                             th0 * f[2] + theta * v[2], th0 * f[3] + theta * v[3]);
            h1 = make_float4(th0 * f[4] + theta * v[4], th0 * f[5] + theta * v[5],
                             th0 * f[6] + theta * v[6], th0 * f[7] + theta * v[7]);
        } else {
            h0 = *(const float4*)(h + off);
            h1 = *(const float4*)(h + off + 4);
            h0.x += theta * v[0]; h0.y += theta * v[1];
            h0.z += theta * v[2]; h0.w += theta * v[3];
            h1.x += theta * v[4]; h1.y += theta * v[5];
            h1.z += theta * v[6]; h1.w += theta * v[7];
        }
        *(float4*)(h + off) = h0;
        *(float4*)(h + off + 4) = h1;
        if (!LAST) {
            uint4 o;
            o.x = pack2(v[0], v[1]);
            o.y = pack2(v[2], v[3]);
            o.z = pack2(v[4], v[5]);
            o.w = pack2(v[6], v[7]);
            *(uint4*)(featout + off) = o;
        }
    }
}

extern "C" void kernel_launch(void* const* d_in, const int* in_sizes, int n_in,
                              void* d_out, int out_size, void* d_ws, size_t ws_size,
                              hipStream_t stream) {
    const float* x  = (const float*)d_in[0];
    const int*   ei = (const int*)d_in[1];   // edge_index [2, E] row-major
    const int N = in_sizes[0] / kF;
    const int E = in_sizes[1] / 2;
    const int* src = ei;
    const int* dst = ei + E;
    float* h = (float*)d_out;

    const int K = (N + BW - 1) >> BSHIFT;         // 196 buckets
    const int cap = 2 * ((E + K - 1) / K);        // per-bucket capacity

    // workspace (~58.4 MB): gcursor | gbase | rp | dinv | csr | xb | featA | featB | pairs
    char* ws = (char*)d_ws;
    size_t off = 0;
    auto carve = [&](size_t bytes) {
        void* p = ws + off;
        off = (off + bytes + 511) & ~(size_t)511;
        return p;
    };
    int*            gcursor = (int*)carve((size_t)K * 4);
    int*            gbase   = (int*)carve((size_t)K * 4);
    int*            rp      = (int*)carve((size_t)(N + 1) * 4);
    float*          dinv    = (float*)carve((size_t)N * 4);
    int*            csr     = (int*)carve((size_t)E * 4);
    unsigned short* xb      = (unsigned short*)carve((size_t)N * kF * 2);
    unsigned short* featA   = (unsigned short*)carve((size_t)N * kF * 2);
    unsigned short* featB   = (unsigned short*)carve((size_t)N * kF * 2);
    unsigned*       pairs   = (unsigned*)carve((size_t)K * cap * 4);

    const float theta[5] = {0.6f, -0.4f, 0.3f, -0.2f, 0.1f};

    // ---- CSR build (multisplit) + x->bf16 convert ----
    k_zero_i<<<1, 256, 0, stream>>>(gcursor, K);
    k_binA<<<(E + TILE - 1) / TILE, 512, 0, stream>>>(src, dst, pairs, gcursor, E, K, cap);
    k_scanb<<<1, 256, 0, stream>>>(gcursor, gbase, K);
    k_binB<<<K, BW, 0, stream>>>(pairs, gcursor, gbase, rp, dinv, csr, N, E, K, cap);
    const int n8 = N * kF / 8;
    k_cvt<<<(n8 + 255) / 256, 256, 0, stream>>>((const float4*)x, (uint4*)xb, n8);

    // ---- 4 fused gather+update passes (k=1 also does init), ping-pong ----
    const int gblocks = (N + 3) / 4;               // 4 waves (nodes) per block
    k_gather<true, false><<<gblocks, 256, 0, stream>>>(rp, csr, xb, x, dinv, featA, h,
                                                       N, theta[0], theta[1]);
    k_gather<false, false><<<gblocks, 256, 0, stream>>>(rp, csr, featA, nullptr, dinv, featB, h,
                                                        N, 0.f, theta[2]);
    k_gather<false, false><<<gblocks, 256, 0, stream>>>(rp, csr, featB, nullptr, dinv, featA, h,
                                                        N, 0.f, theta[3]);
    k_gather<false, true><<<gblocks, 256, 0, stream>>>(rp, csr, featA, nullptr, dinv, nullptr, h,
                                                       N, 0.f, theta[4]);
}

// Round 6
// 293.200 us; speedup vs baseline: 5.5768x; 1.0878x over previous
//
#include <hip/hip_runtime.h>

// PolyConv: h = sum_k theta[k] * L_sym^k x,  L_sym = I - D^{-1/2} A D^{-1/2}
// N=100000 nodes, E=1600000 edges, F=64 features, 5 theta terms.
//
// Round 6: k_gather processes TWO nodes per wave (half-wave each: 4 rows x
// 8-lane 16B slices). Cuts per-node wave-instruction count ~35%: butterfly
// 3 levels -> 2 (24 -> 8 shfl/node), epilogue lanes 8 -> 16, loop overhead
// amortized over the pair. Preamble: binA TILE 8192->4096 (391 blocks, fills
// 256 CUs), binB writes csr directly through L2 (no LDS staging) and computes
// its own gbase scan (k_scanb launch removed).

constexpr int kF = 64;
constexpr int BSHIFT = 9;             // bucket = dst >> 9  (512 nodes/bucket)
constexpr int BW = 1 << BSHIFT;       // 512
constexpr int TILE = 4096;            // edges per phase-A block

static __device__ __forceinline__ float bfl(unsigned u) {        // low bf16 -> f32
    return __uint_as_float(u << 16);
}
static __device__ __forceinline__ float bfh(unsigned u) {        // high bf16 -> f32
    return __uint_as_float(u & 0xffff0000u);
}
static __device__ __forceinline__ unsigned f2bf(float f) {       // RNE f32 -> bf16
    unsigned u = __float_as_uint(f);
    return (u + 0x7fffu + ((u >> 16) & 1u)) >> 16;
}
static __device__ __forceinline__ unsigned pack2(float a, float b) {
    return f2bf(a) | (f2bf(b) << 16);
}

__global__ void k_zero_i(int* __restrict__ p, int n) {
    int i = blockIdx.x * blockDim.x + threadIdx.x;
    if (i < n) p[i] = 0;
}

// x (fp32) -> xb (bf16), 8 elements per thread.
__global__ void k_cvt(const float4* __restrict__ x4, uint4* __restrict__ xb4, int n8) {
    int i = blockIdx.x * blockDim.x + threadIdx.x;
    if (i < n8) {
        float4 a = x4[2 * i];
        float4 b = x4[2 * i + 1];
        uint4 o;
        o.x = pack2(a.x, a.y);
        o.y = pack2(a.z, a.w);
        o.z = pack2(b.x, b.y);
        o.w = pack2(b.z, b.w);
        xb4[i] = o;
    }
}

// Phase A: multisplit edges into K buckets (LDS-staged, line-dense writes).
// blockDim = 512, TILE = 4096 edges (8/thread), 391 blocks.
__global__ void k_binA(const int* __restrict__ src, const int* __restrict__ dst,
                       unsigned* __restrict__ pairs, int* __restrict__ gcursor,
                       int E, int K, int cap) {
    __shared__ unsigned sorted[TILE];   // 16 KB
    __shared__ int hist[256];
    __shared__ int stmp[256];
    __shared__ int loff[257];
    __shared__ int lcur[256];
    __shared__ int gb[256];
    const int tid = threadIdx.x;        // blockDim = 512
    const long long tb = (long long)blockIdx.x * TILE;
    const int tcount = (int)min((long long)TILE, (long long)E - tb);

    if (tid < 256) hist[tid] = 0;
    __syncthreads();
    for (int i = tid; i < tcount; i += 512)
        atomicAdd(&hist[dst[tb + i] >> BSHIFT], 1);
    __syncthreads();
    int v = (tid < 256) ? hist[tid] : 0;
    if (tid < 256) stmp[tid] = v;
    __syncthreads();
    for (int o = 1; o < 256; o <<= 1) {
        int t = (tid >= o && tid < 256) ? stmp[tid - o] : 0;
        __syncthreads();
        if (tid < 256) stmp[tid] += t;
        __syncthreads();
    }
    if (tid < 256) {
        loff[tid] = stmp[tid] - v;
        lcur[tid] = stmp[tid] - v;
        gb[tid] = (tid < K) ? atomicAdd(&gcursor[tid], v) : 0;
        if (tid == 255) loff[256] = stmp[255];
    }
    __syncthreads();
    for (int i = tid; i < tcount; i += 512) {
        int d = dst[tb + i];
        int s = src[tb + i];
        int b = d >> BSHIFT;
        int pos = atomicAdd(&lcur[b], 1);
        sorted[pos] = ((unsigned)(d & (BW - 1)) << 23) | (unsigned)s;
    }
    __syncthreads();
    for (int i = tid; i < tcount; i += 512) {
        int lo = 0, hi = K - 1;
        while (lo < hi) {
            int mid = (lo + hi + 1) >> 1;
            if (loff[mid] <= i) lo = mid; else hi = mid - 1;
        }
        pairs[(size_t)lo * cap + gb[lo] + (i - loff[lo])] = sorted[i];
    }
}

// Phase B: one block (512 threads) per bucket. Computes gbase scan itself,
// per-node counts -> LDS scan -> direct scatter to csr (region is ~32KB,
// L2-resident so writes combine), emits rp + dinv.
__global__ void k_binB(const unsigned* __restrict__ pairs, const int* __restrict__ gcursor,
                       int* __restrict__ rp, float* __restrict__ dinv,
                       int* __restrict__ csr, int N, int E, int K, int cap) {
    __shared__ int gsc[256];
    __shared__ int cnt[BW];
    __shared__ int stmp[BW];
    __shared__ int excl[BW];
    __shared__ int cur[BW];
    const int b = blockIdx.x;
    const int tid = threadIdx.x;        // blockDim = 512

    // exclusive-scan gcursor (K <= 256) to get this bucket's base
    int gv = (tid < 256) ? ((tid < K) ? gcursor[tid] : 0) : 0;
    if (tid < 256) gsc[tid] = gv;
    __syncthreads();
    for (int o = 1; o < 256; o <<= 1) {
        int t = (tid >= o && tid < 256) ? gsc[tid - o] : 0;
        __syncthreads();
        if (tid < 256) gsc[tid] += t;
        __syncthreads();
    }
    const int ecnt = gcursor[b];
    const int base = gsc[b] - ecnt;     // inclusive - own = exclusive
    const unsigned* bp = pairs + (size_t)b * cap;

    cnt[tid] = 0;
    __syncthreads();
    for (int i = tid; i < ecnt; i += BW)
        atomicAdd(&cnt[bp[i] >> 23], 1);
    __syncthreads();
    int v = cnt[tid];
    stmp[tid] = v;
    __syncthreads();
    for (int o = 1; o < BW; o <<= 1) {
        int t = (tid >= o) ? stmp[tid - o] : 0;
        __syncthreads();
        stmp[tid] += t;
        __syncthreads();
    }
    excl[tid] = stmp[tid] - v;
    cur[tid] = stmp[tid] - v;
    __syncthreads();
    for (int i = tid; i < ecnt; i += BW) {
        unsigned p = bp[i];
        int pos = atomicAdd(&cur[p >> 23], 1);
        csr[base + pos] = (int)(p & 0x7FFFFFu);    // L2-resident 32KB region
    }
    int node = (b << BSHIFT) + tid;
    if (node < N) {
        rp[node] = base + excl[tid];
        dinv[node] = rsqrtf(fmaxf((float)v, 1.0f));
    }
    if (b == K - 1 && tid == 0) rp[N] = E;
}

// TWO nodes per wave, bf16 feature table (128B rows).
// Lane l: half = l>>5 (node pair member), r = (l>>3)&3 (one of 4 rows per
// iteration per node), c = l&7 (16B = 8 features). Each wave-iteration
// gathers 8 rows total (1KB). Butterfly over lanes ^8,^16 (stays within a
// half) leaves lanes {0..7, 32..39} holding complete feature sums.
// Epilogue: v = feat[d] - dinv[d]*acc; FIRST uses fp32 x for the identity
// term and writes h fresh (poison-safe); !LAST stores v as bf16.
template <bool FIRST, bool LAST>
__global__ void k_gather(const int* __restrict__ rp, const int* __restrict__ csr,
                         const unsigned short* __restrict__ featin,
                         const float* __restrict__ xf,
                         const float* __restrict__ dinv,
                         unsigned short* __restrict__ featout,
                         float* __restrict__ h,
                         int n, float th0, float theta) {
    int wid = (blockIdx.x * blockDim.x + threadIdx.x) >> 6;
    int lane = threadIdx.x & 63;
    int half = lane >> 5;
    int r = (lane >> 3) & 3;
    int c = lane & 7;
    int node = wid * 2 + half;
    if (wid * 2 >= n) return;
    bool valid = node < n;
    int beg = valid ? rp[node] : 0;
    int end = valid ? rp[node + 1] : 0;
    int len = end - beg;
    int olen = __shfl_xor(len, 32, 64);
    int mlen = (len > olen) ? len : olen;   // pair max -> uniform trip count

    float acc[8] = {0.f, 0.f, 0.f, 0.f, 0.f, 0.f, 0.f, 0.f};
    for (int i = 0; i < mlen; i += 4) {
        int j = beg + i + r;
        bool ok = j < end;
        int jj = ok ? j : 0;                 // csr[0] always valid; w=0 masks
        int s = csr[jj];
        float w = ok ? dinv[s] : 0.0f;
        uint4 rr = *(const uint4*)(featin + ((size_t)s << 6) + (c << 3));
        acc[0] += w * bfl(rr.x);
        acc[1] += w * bfh(rr.x);
        acc[2] += w * bfl(rr.y);
        acc[3] += w * bfh(rr.y);
        acc[4] += w * bfl(rr.z);
        acc[5] += w * bfh(rr.z);
        acc[6] += w * bfl(rr.w);
        acc[7] += w * bfh(rr.w);
    }
    #pragma unroll
    for (int m = 8; m <= 16; m <<= 1) {
        #pragma unroll
        for (int i = 0; i < 8; ++i)
            acc[i] += __shfl_xor(acc[i], m, 64);
    }

    if (r == 0 && valid) {                   // lanes 0..7 and 32..39
        size_t off = ((size_t)node << 6) + (c << 3);
        float f[8];
        if (FIRST) {
            float4 a = *(const float4*)(xf + off);
            float4 b = *(const float4*)(xf + off + 4);
            f[0] = a.x; f[1] = a.y; f[2] = a.z; f[3] = a.w;
            f[4] = b.x; f[5] = b.y; f[6] = b.z; f[7] = b.w;
        } else {
            uint4 rr = *(const uint4*)(featin + off);
            f[0] = bfl(rr.x); f[1] = bfh(rr.x);
            f[2] = bfl(rr.y); f[3] = bfh(rr.y);
            f[4] = bfl(rr.z); f[5] = bfh(rr.z);
            f[6] = bfl(rr.w); f[7] = bfh(rr.w);
        }
        float di = dinv[node];
        float v[8];
        #pragma unroll
        for (int i = 0; i < 8; ++i) v[i] = f[i] - di * acc[i];
        float4 h0, h1;
        if (FIRST) {
            h0 = make_float4(th0 * f[0] + theta * v[0], th0 * f[1] + theta * v[1],
                             th0 * f[2] + theta * v[2], th0 * f[3] + theta * v[3]);
            h1 = make_float4(th0 * f[4] + theta * v[4], th0 * f[5] + theta * v[5],
                             th0 * f[6] + theta * v[6], th0 * f[7] + theta * v[7]);
        } else {
            h0 = *(const float4*)(h + off);
            h1 = *(const float4*)(h + off + 4);
            h0.x += theta * v[0]; h0.y += theta * v[1];
            h0.z += theta * v[2]; h0.w += theta * v[3];
            h1.x += theta * v[4]; h1.y += theta * v[5];
            h1.z += theta * v[6]; h1.w += theta * v[7];
        }
        *(float4*)(h + off) = h0;
        *(float4*)(h + off + 4) = h1;
        if (!LAST) {
            uint4 o;
            o.x = pack2(v[0], v[1]);
            o.y = pack2(v[2], v[3]);
            o.z = pack2(v[4], v[5]);
            o.w = pack2(v[6], v[7]);
            *(uint4*)(featout + off) = o;
        }
    }
}

extern "C" void kernel_launch(void* const* d_in, const int* in_sizes, int n_in,
                              void* d_out, int out_size, void* d_ws, size_t ws_size,
                              hipStream_t stream) {
    const float* x  = (const float*)d_in[0];
    const int*   ei = (const int*)d_in[1];   // edge_index [2, E] row-major
    const int N = in_sizes[0] / kF;
    const int E = in_sizes[1] / 2;
    const int* src = ei;
    const int* dst = ei + E;
    float* h = (float*)d_out;

    const int K = (N + BW - 1) >> BSHIFT;         // 196 buckets
    const int cap = 2 * ((E + K - 1) / K);        // per-bucket capacity

    // workspace (~58 MB): gcursor | rp | dinv | csr | xb | featA | featB | pairs
    char* ws = (char*)d_ws;
    size_t off = 0;
    auto carve = [&](size_t bytes) {
        void* p = ws + off;
        off = (off + bytes + 511) & ~(size_t)511;
        return p;
    };
    int*            gcursor = (int*)carve((size_t)K * 4);
    int*            rp      = (int*)carve((size_t)(N + 1) * 4);
    float*          dinv    = (float*)carve((size_t)N * 4);
    int*            csr     = (int*)carve((size_t)E * 4);
    unsigned short* xb      = (unsigned short*)carve((size_t)N * kF * 2);
    unsigned short* featA   = (unsigned short*)carve((size_t)N * kF * 2);
    unsigned short* featB   = (unsigned short*)carve((size_t)N * kF * 2);
    unsigned*       pairs   = (unsigned*)carve((size_t)K * cap * 4);

    const float theta[5] = {0.6f, -0.4f, 0.3f, -0.2f, 0.1f};

    // ---- CSR build (multisplit) + x->bf16 convert ----
    k_zero_i<<<1, 256, 0, stream>>>(gcursor, K);
    k_binA<<<(E + TILE - 1) / TILE, 512, 0, stream>>>(src, dst, pairs, gcursor, E, K, cap);
    k_binB<<<K, BW, 0, stream>>>(pairs, gcursor, rp, dinv, csr, N, E, K, cap);
    const int n8 = N * kF / 8;
    k_cvt<<<(n8 + 255) / 256, 256, 0, stream>>>((const float4*)x, (uint4*)xb, n8);

    // ---- 4 fused gather+update passes (k=1 also does init), ping-pong ----
    const int nwaves = (N + 1) / 2;                // 2 nodes per wave
    const int gblocks = (nwaves + 3) / 4;          // 4 waves per 256-thread block
    k_gather<true, false><<<gblocks, 256, 0, stream>>>(rp, csr, xb, x, dinv, featA, h,
                                                       N, theta[0], theta[1]);
    k_gather<false, false><<<gblocks, 256, 0, stream>>>(rp, csr, featA, nullptr, dinv, featB, h,
                                                        N, 0.f, theta[2]);
    k_gather<false, false><<<gblocks, 256, 0, stream>>>(rp, csr, featB, nullptr, dinv, featA, h,
                                                        N, 0.f, theta[3]);
    k_gather<false, true><<<gblocks, 256, 0, stream>>>(rp, csr, featA, nullptr, dinv, nullptr, h,
                                                       N, 0.f, theta[4]);
}

// Round 7
// 273.940 us; speedup vs baseline: 5.9689x; 1.0703x over previous
//
#include <hip/hip_runtime.h>

// PolyConv: h = sum_k theta[k] * L_sym^k x,  L_sym = I - D^{-1/2} A D^{-1/2}
// N=100000 nodes, E=1600000 edges, F=64 features, 5 theta terms.
//
// Round 7: (1) gather K-loop unrolled x2 -> two independent uint4 gathers in
// flight per iteration (halves dependent-latency waits; loop was MLP=1);
// (2) binB buckets 512->256 nodes => K=391 blocks (fills 256 CUs, was 196);
// (3) x->bf16 convert fused into binA (removes k_cvt launch).

constexpr int kF = 64;
constexpr int BSHIFT = 8;             // bucket = dst >> 8  (256 nodes/bucket)
constexpr int NB = 1 << BSHIFT;       // 256 nodes per bucket
constexpr int TILE = 4096;            // edges per phase-A block
constexpr int KMAX = 512;             // array bound for K (=391)

static __device__ __forceinline__ float bfl(unsigned u) {        // low bf16 -> f32
    return __uint_as_float(u << 16);
}
static __device__ __forceinline__ float bfh(unsigned u) {        // high bf16 -> f32
    return __uint_as_float(u & 0xffff0000u);
}
static __device__ __forceinline__ unsigned f2bf(float f) {       // RNE f32 -> bf16
    unsigned u = __float_as_uint(f);
    return (u + 0x7fffu + ((u >> 16) & 1u)) >> 16;
}
static __device__ __forceinline__ unsigned pack2(float a, float b) {
    return f2bf(a) | (f2bf(b) << 16);
}

__global__ void k_zero_i(int* __restrict__ p, int n) {
    int i = blockIdx.x * blockDim.x + threadIdx.x;
    if (i < n) p[i] = 0;
}

// Phase A: multisplit edges into K buckets (LDS-staged, line-dense writes).
// blockDim = 512, TILE = 4096 edges (8/thread), 391 blocks.
// Also converts a disjoint slice of x (fp32) -> xb (bf16): streaming work
// that overlaps the LDS-atomic-latency-bound histogram/scatter phases.
__global__ void k_binA(const int* __restrict__ src, const int* __restrict__ dst,
                       unsigned* __restrict__ pairs, int* __restrict__ gcursor,
                       const float4* __restrict__ x4, uint4* __restrict__ xb4,
                       int n8, int E, int K, int cap) {
    __shared__ unsigned sorted[TILE];   // 16 KB
    __shared__ int hist[KMAX];
    __shared__ int stmp[KMAX];
    __shared__ int loff[KMAX + 1];
    __shared__ int lcur[KMAX];
    __shared__ int gb[KMAX];
    const int tid = threadIdx.x;        // blockDim = 512
    const long long tb = (long long)blockIdx.x * TILE;
    const int tcount = (int)min((long long)TILE, (long long)E - tb);

    // fused x -> bf16 convert (disjoint slice per block)
    {
        int per = (n8 + gridDim.x - 1) / (int)gridDim.x;
        int b0 = blockIdx.x * per;
        int b1 = min(b0 + per, n8);
        for (int i = b0 + tid; i < b1; i += 512) {
            float4 a = x4[2 * i];
            float4 b = x4[2 * i + 1];
            uint4 o;
            o.x = pack2(a.x, a.y);
            o.y = pack2(a.z, a.w);
            o.z = pack2(b.x, b.y);
            o.w = pack2(b.z, b.w);
            xb4[i] = o;
        }
    }

    hist[tid] = 0;
    __syncthreads();
    for (int i = tid; i < tcount; i += 512)
        atomicAdd(&hist[dst[tb + i] >> BSHIFT], 1);
    __syncthreads();
    int v = hist[tid];
    stmp[tid] = v;
    __syncthreads();
    for (int o = 1; o < KMAX; o <<= 1) {
        int t = (tid >= o) ? stmp[tid - o] : 0;
        __syncthreads();
        stmp[tid] += t;
        __syncthreads();
    }
    loff[tid] = stmp[tid] - v;
    lcur[tid] = stmp[tid] - v;
    gb[tid] = (tid < K) ? atomicAdd(&gcursor[tid], v) : 0;
    if (tid == KMAX - 1) loff[KMAX] = stmp[KMAX - 1];
    __syncthreads();
    for (int i = tid; i < tcount; i += 512) {
        int d = dst[tb + i];
        int s = src[tb + i];
        int b = d >> BSHIFT;
        int pos = atomicAdd(&lcur[b], 1);
        sorted[pos] = ((unsigned)(d & (NB - 1)) << 23) | (unsigned)s;
    }
    __syncthreads();
    for (int i = tid; i < tcount; i += 512) {
        int lo = 0, hi = K - 1;
        while (lo < hi) {
            int mid = (lo + hi + 1) >> 1;
            if (loff[mid] <= i) lo = mid; else hi = mid - 1;
        }
        pairs[(size_t)lo * cap + gb[lo] + (i - loff[lo])] = sorted[i];
    }
}

// Phase B: one block (512 threads) per bucket of 256 nodes (K=391 blocks).
// Computes gbase scan in-kernel, per-node counts -> LDS scan -> direct
// scatter to csr (bucket region ~16KB, L2-resident), emits rp + dinv.
__global__ void k_binB(const unsigned* __restrict__ pairs, const int* __restrict__ gcursor,
                       int* __restrict__ rp, float* __restrict__ dinv,
                       int* __restrict__ csr, int N, int E, int K, int cap) {
    __shared__ int gsc[KMAX];
    __shared__ int cnt[NB];
    __shared__ int stmp[NB];
    __shared__ int excl[NB];
    __shared__ int cur[NB];
    const int b = blockIdx.x;
    const int tid = threadIdx.x;        // blockDim = 512

    // exclusive-scan gcursor (K <= 512) for this bucket's base
    int gv = (tid < K) ? gcursor[tid] : 0;
    gsc[tid] = gv;
    __syncthreads();
    for (int o = 1; o < KMAX; o <<= 1) {
        int t = (tid >= o) ? gsc[tid - o] : 0;
        __syncthreads();
        gsc[tid] += t;
        __syncthreads();
    }
    const int ecnt = gcursor[b];
    const int base = gsc[b] - ecnt;     // inclusive - own = exclusive
    const unsigned* bp = pairs + (size_t)b * cap;

    if (tid < NB) cnt[tid] = 0;
    __syncthreads();
    for (int i = tid; i < ecnt; i += 512)
        atomicAdd(&cnt[bp[i] >> 23], 1);
    __syncthreads();
    int v = (tid < NB) ? cnt[tid] : 0;
    if (tid < NB) stmp[tid] = v;
    __syncthreads();
    for (int o = 1; o < NB; o <<= 1) {
        int t = (tid >= o && tid < NB) ? stmp[tid - o] : 0;
        __syncthreads();
        if (tid < NB) stmp[tid] += t;
        __syncthreads();
    }
    if (tid < NB) {
        excl[tid] = stmp[tid] - v;
        cur[tid] = stmp[tid] - v;
    }
    __syncthreads();
    for (int i = tid; i < ecnt; i += 512) {
        unsigned p = bp[i];
        int pos = atomicAdd(&cur[p >> 23], 1);
        csr[base + pos] = (int)(p & 0x7FFFFFu);    // L2-resident 16KB region
    }
    int node = (b << BSHIFT) + tid;
    if (tid < NB && node < N) {
        rp[node] = base + excl[tid];
        dinv[node] = rsqrtf(fmaxf((float)v, 1.0f));
    }
    if (b == K - 1 && tid == 0) rp[N] = E;
}

// TWO nodes per wave, bf16 feature table (128B rows), K-loop unrolled x2.
// Lane l: half = l>>5 (node of the pair), r = (l>>3)&3 (row within batch),
// c = l&7 (16B = 8 features). Each iteration gathers 2x8 rows (2KB in
// flight). Butterfly over lanes ^8,^16 leaves lanes {0..7, 32..39} complete.
template <bool FIRST, bool LAST>
__global__ void k_gather(const int* __restrict__ rp, const int* __restrict__ csr,
                         const unsigned short* __restrict__ featin,
                         const float* __restrict__ xf,
                         const float* __restrict__ dinv,
                         unsigned short* __restrict__ featout,
                         float* __restrict__ h,
                         int n, float th0, float theta) {
    int wid = (blockIdx.x * blockDim.x + threadIdx.x) >> 6;
    int lane = threadIdx.x & 63;
    int half = lane >> 5;
    int r = (lane >> 3) & 3;
    int c = lane & 7;
    int node = wid * 2 + half;
    if (wid * 2 >= n) return;
    bool valid = node < n;
    int beg = valid ? rp[node] : 0;
    int end = valid ? rp[node + 1] : 0;
    int len = end - beg;
    int olen = __shfl_xor(len, 32, 64);
    int mlen = (len > olen) ? len : olen;   // pair max -> uniform trip count

    float acc[8] = {0.f, 0.f, 0.f, 0.f, 0.f, 0.f, 0.f, 0.f};
    for (int i = 0; i < mlen; i += 8) {
        int j1 = beg + i + r;
        int j2 = j1 + 4;
        bool ok1 = j1 < end;
        bool ok2 = j2 < end;
        int s1 = csr[ok1 ? j1 : 0];
        int s2 = csr[ok2 ? j2 : 0];
        float w1 = ok1 ? dinv[s1] : 0.0f;
        float w2 = ok2 ? dinv[s2] : 0.0f;
        uint4 ra = *(const uint4*)(featin + ((size_t)s1 << 6) + (c << 3));
        uint4 rb = *(const uint4*)(featin + ((size_t)s2 << 6) + (c << 3));
        acc[0] += w1 * bfl(ra.x);
        acc[1] += w1 * bfh(ra.x);
        acc[2] += w1 * bfl(ra.y);
        acc[3] += w1 * bfh(ra.y);
        acc[4] += w1 * bfl(ra.z);
        acc[5] += w1 * bfh(ra.z);
        acc[6] += w1 * bfl(ra.w);
        acc[7] += w1 * bfh(ra.w);
        acc[0] += w2 * bfl(rb.x);
        acc[1] += w2 * bfh(rb.x);
        acc[2] += w2 * bfl(rb.y);
        acc[3] += w2 * bfh(rb.y);
        acc[4] += w2 * bfl(rb.z);
        acc[5] += w2 * bfh(rb.z);
        acc[6] += w2 * bfl(rb.w);
        acc[7] += w2 * bfh(rb.w);
    }
    #pragma unroll
    for (int m = 8; m <= 16; m <<= 1) {
        #pragma unroll
        for (int i = 0; i < 8; ++i)
            acc[i] += __shfl_xor(acc[i], m, 64);
    }

    if (r == 0 && valid) {                   // lanes 0..7 and 32..39
        size_t off = ((size_t)node << 6) + (c << 3);
        float f[8];
        if (FIRST) {
            float4 a = *(const float4*)(xf + off);
            float4 b = *(const float4*)(xf + off + 4);
            f[0] = a.x; f[1] = a.y; f[2] = a.z; f[3] = a.w;
            f[4] = b.x; f[5] = b.y; f[6] = b.z; f[7] = b.w;
        } else {
            uint4 rr = *(const uint4*)(featin + off);
            f[0] = bfl(rr.x); f[1] = bfh(rr.x);
            f[2] = bfl(rr.y); f[3] = bfh(rr.y);
            f[4] = bfl(rr.z); f[5] = bfh(rr.z);
            f[6] = bfl(rr.w); f[7] = bfh(rr.w);
        }
        float di = dinv[node];
        float v[8];
        #pragma unroll
        for (int i = 0; i < 8; ++i) v[i] = f[i] - di * acc[i];
        float4 h0, h1;
        if (FIRST) {
            h0 = make_float4(th0 * f[0] + theta * v[0], th0 * f[1] + theta * v[1],
                             th0 * f[2] + theta * v[2], th0 * f[3] + theta * v[3]);
            h1 = make_float4(th0 * f[4] + theta * v[4], th0 * f[5] + theta * v[5],
                             th0 * f[6] + theta * v[6], th0 * f[7] + theta * v[7]);
        } else {
            h0 = *(const float4*)(h + off);
            h1 = *(const float4*)(h + off + 4);
            h0.x += theta * v[0]; h0.y += theta * v[1];
            h0.z += theta * v[2]; h0.w += theta * v[3];
            h1.x += theta * v[4]; h1.y += theta * v[5];
            h1.z += theta * v[6]; h1.w += theta * v[7];
        }
        *(float4*)(h + off) = h0;
        *(float4*)(h + off + 4) = h1;
        if (!LAST) {
            uint4 o;
            o.x = pack2(v[0], v[1]);
            o.y = pack2(v[2], v[3]);
            o.z = pack2(v[4], v[5]);
            o.w = pack2(v[6], v[7]);
            *(uint4*)(featout + off) = o;
        }
    }
}

extern "C" void kernel_launch(void* const* d_in, const int* in_sizes, int n_in,
                              void* d_out, int out_size, void* d_ws, size_t ws_size,
                              hipStream_t stream) {
    const float* x  = (const float*)d_in[0];
    const int*   ei = (const int*)d_in[1];   // edge_index [2, E] row-major
    const int N = in_sizes[0] / kF;
    const int E = in_sizes[1] / 2;
    const int* src = ei;
    const int* dst = ei + E;
    float* h = (float*)d_out;

    const int K = (N + NB - 1) >> BSHIFT;         // 391 buckets (K <= KMAX)
    const int cap = 2 * ((E + K - 1) / K);        // per-bucket capacity

    // workspace (~58 MB): gcursor | rp | dinv | csr | xb | featA | featB | pairs
    char* ws = (char*)d_ws;
    size_t off = 0;
    auto carve = [&](size_t bytes) {
        void* p = ws + off;
        off = (off + bytes + 511) & ~(size_t)511;
        return p;
    };
    int*            gcursor = (int*)carve((size_t)K * 4);
    int*            rp      = (int*)carve((size_t)(N + 1) * 4);
    float*          dinv    = (float*)carve((size_t)N * 4);
    int*            csr     = (int*)carve((size_t)E * 4);
    unsigned short* xb      = (unsigned short*)carve((size_t)N * kF * 2);
    unsigned short* featA   = (unsigned short*)carve((size_t)N * kF * 2);
    unsigned short* featB   = (unsigned short*)carve((size_t)N * kF * 2);
    unsigned*       pairs   = (unsigned*)carve((size_t)K * cap * 4);

    const float theta[5] = {0.6f, -0.4f, 0.3f, -0.2f, 0.1f};

    // ---- CSR build (multisplit) with fused x->bf16 convert ----
    const int n8 = N * kF / 8;
    k_zero_i<<<1, 512, 0, stream>>>(gcursor, K);
    k_binA<<<(E + TILE - 1) / TILE, 512, 0, stream>>>(src, dst, pairs, gcursor,
                                                      (const float4*)x, (uint4*)xb,
                                                      n8, E, K, cap);
    k_binB<<<K, 512, 0, stream>>>(pairs, gcursor, rp, dinv, csr, N, E, K, cap);

    // ---- 4 fused gather+update passes (k=1 also does init), ping-pong ----
    const int nwaves = (N + 1) / 2;                // 2 nodes per wave
    const int gblocks = (nwaves + 3) / 4;          // 4 waves per 256-thread block
    k_gather<true, false><<<gblocks, 256, 0, stream>>>(rp, csr, xb, x, dinv, featA, h,
                                                       N, theta[0], theta[1]);
    k_gather<false, false><<<gblocks, 256, 0, stream>>>(rp, csr, featA, nullptr, dinv, featB, h,
                                                        N, 0.f, theta[2]);
    k_gather<false, false><<<gblocks, 256, 0, stream>>>(rp, csr, featB, nullptr, dinv, featA, h,
                                                        N, 0.f, theta[3]);
    k_gather<false, true><<<gblocks, 256, 0, stream>>>(rp, csr, featA, nullptr, dinv, nullptr, h,
                                                       N, 0.f, theta[4]);
}